// Round 1
// baseline (171.017 us; speedup 1.0000x reference)
//
#include <hip/hip_runtime.h>
#include <hip/hip_bf16.h>

// Problem constants (from reference)
#define PCR0   (-51.2f)
#define PCR1   (-51.2f)
#define VX_    (0.05f)
#define VY_    (0.05f)
#define STRIDE_ 4.0f
#define FW_    512
#define FH_    512
#define NCLS   10
#define NOBJ   500
#define OVERLAP_ 0.1f
#define MINRAD 2
#define RMAX_  16
#define BATCH_ 16
#define EPS_   1.1920928955078125e-07f   // np.finfo(float32).eps

// Flat output layout (all stored as float32 elements)
#define HEATMAP_ELEMS  (BATCH_ * NCLS * FH_ * FW_)       // 41,943,040
#define RETBOX_OFF     HEATMAP_ELEMS
#define RETBOX_ELEMS   (BATCH_ * NOBJ * 8)               // 64,000
#define INDS_OFF       (RETBOX_OFF + RETBOX_ELEMS)       // 42,007,040
#define MASK_OFF       (INDS_OFF + BATCH_ * NOBJ)        // 42,015,040

// Bins: (class, 32-row band) per batch. Slab = contiguous 64 KB.
#define BAND_  32
#define NBAND  (FH_ / BAND_)                 // 16
#define BIN_N  (NCLS * NBAND)                // 160 bins per batch
#define NBINS  (BATCH_ * BIN_N)              // 2560 blocks for phaseB
#define RECMAX 1000                          // 500 objs x <=2 bands each

// ws layout: per batch: cnt[160], off[160], rec[1000] (int4)
#define BSTRIDE     (2 * BIN_N + RECMAX * 4)             // ints per batch = 4320
#define WS_NEEDED   ((size_t)BATCH_ * BSTRIDE * 4)       // 276,480 B

// ---------------------------------------------------------------------------
// Per-object math (identical arithmetic to prior rounds so truncation
// boundaries don't move).
// ---------------------------------------------------------------------------
__device__ __forceinline__ void obj_params(
        float x, float y, float dx, float dy,
        float& coord_x, float& coord_y, int& cxi, int& cyi,
        int& radius, bool& valid)
{
    coord_x = fminf(fmaxf((x - PCR0) / VX_ / STRIDE_, 0.f), (float)FW_ - 0.5f);
    coord_y = fminf(fmaxf((y - PCR1) / VY_ / STRIDE_, 0.f), (float)FH_ - 0.5f);
    cxi = (int)coord_x;
    cyi = (int)coord_y;

    float dxf = dx / VX_ / STRIDE_;
    float dyf = dy / VY_ / STRIDE_;

    const float h = dxf, w = dyf, o = OVERLAP_;
    float b1 = h + w;
    float c1 = w * h * (1.f - o) / (1.f + o);
    float r1 = (b1 + sqrtf(fmaxf(b1 * b1 - 4.f * c1, 0.f))) * 0.5f;
    float b2 = 2.f * (h + w);
    float c2 = (1.f - o) * w * h;
    float r2 = (b2 + sqrtf(fmaxf(b2 * b2 - 16.f * c2, 0.f))) * 0.5f;
    float a3 = 4.f * o;
    float b3 = -2.f * o * (h + w);
    float c3 = (o - 1.f) * w * h;
    float r3 = (b3 + sqrtf(fmaxf(b3 * b3 - 4.f * a3 * c3, 0.f))) / (2.f * a3);
    float radf = fminf(fminf(r1, r2), r3);
    radius = (int)radf;
    radius = min(max(radius, MINRAD), RMAX_);

    valid = (dxf > 0.f) && (dyf > 0.f) &&
            (cxi >= 0) && (cxi <= FW_) && (cyi >= 0) && (cyi <= FH_);
}

// ---------------------------------------------------------------------------
// Phase A: one block per batch (16 blocks x 512). Scans the batch ONCE:
// writes ret_boxes/inds/mask, buckets records into per-(class,band) compact
// segments in LDS (count -> wave-shuffle prefix scan -> place), streams
// cnt/off/rec to ws. float4 loads of gt, float4 stores of ret_boxes.
// ---------------------------------------------------------------------------
__global__ __launch_bounds__(512) void phaseA(
        const float* __restrict__ gt, float* __restrict__ out,
        int* __restrict__ bins)
{
    const int b = blockIdx.x;
    const int t = threadIdx.x;

    __shared__ int  s_cnt[BIN_N], s_off[BIN_N], s_pos[BIN_N];
    __shared__ int4 s_rec[RECMAX];

    if (t < BIN_N) { s_cnt[t] = 0; s_pos[t] = 0; }
    __syncthreads();

    bool valid = false; int c = 0, ty0 = 0, ty1 = -1; int4 rec;
    if (t < NOBJ) {
        const int obj = b * NOBJ + t;
        const float4 lo = *(const float4*)(gt + (size_t)obj * 8);
        const float4 hi = *(const float4*)(gt + (size_t)obj * 8 + 4);
        // lo = {x, y, z, dx}, hi = {dy, dz, heading, cls}
        float coord_x, coord_y; int cxi, cyi, radius;
        obj_params(lo.x, lo.y, lo.w, hi.x, coord_x, coord_y, cxi, cyi, radius, valid);
        c = min(max((int)(hi.w - 1.0f), 0), NCLS - 1);

        // per-object outputs (vectorized)
        float vf = valid ? 1.f : 0.f;
        float4 rb0 = make_float4((coord_x - (float)cxi) * vf,
                                 (coord_y - (float)cyi) * vf,
                                 lo.z * vf,
                                 logf(fmaxf(lo.w, 1e-12f)) * vf);
        float4 rb1 = make_float4(logf(fmaxf(hi.x, 1e-12f)) * vf,
                                 logf(fmaxf(hi.y, 1e-12f)) * vf,
                                 cosf(hi.z) * vf,
                                 sinf(hi.z) * vf);
        float* rb = out + RETBOX_OFF + (size_t)obj * 8;
        *(float4*)(rb)     = rb0;
        *(float4*)(rb + 4) = rb1;
        out[INDS_OFF + obj] = valid ? (float)(cyi * FW_ + cxi) : 0.f;
        out[MASK_OFF + obj] = vf;

        if (valid) {
            float sigma = (2.f * (float)radius + 1.f) / 6.f;
            float negInv = -1.0f / (2.f * sigma * sigma);
            rec = make_int4(cxi, cyi, radius, __float_as_int(negInv));
            ty0 = max(cyi - radius, 0) >> 5;
            ty1 = min(cyi + radius, FH_ - 1) >> 5;   // ty1 <= ty0+1 (33 rows)
            for (int ty = ty0; ty <= ty1; ++ty)
                atomicAdd(&s_cnt[c * NBAND + ty], 1);
        }
    }
    __syncthreads();

    // Exclusive prefix over 160 bins: wave 0 only, 3 bins/lane + shfl scan.
    if (t < 64) {
        int base = t * 3;                      // 64*3 = 192 >= 160
        int c0 = (base + 0 < BIN_N) ? s_cnt[base + 0] : 0;
        int c1 = (base + 1 < BIN_N) ? s_cnt[base + 1] : 0;
        int c2 = (base + 2 < BIN_N) ? s_cnt[base + 2] : 0;
        int sum = c0 + c1 + c2;
        int s = sum;
        #pragma unroll
        for (int d = 1; d < 64; d <<= 1) {
            int u = __shfl_up(s, d);
            if (t >= d) s += u;
        }
        int excl = s - sum;
        if (base + 0 < BIN_N) s_off[base + 0] = excl;
        if (base + 1 < BIN_N) s_off[base + 1] = excl + c0;
        if (base + 2 < BIN_N) s_off[base + 2] = excl + c0 + c1;
    }
    __syncthreads();

    if (valid) {
        for (int ty = ty0; ty <= ty1; ++ty) {
            int bin = c * NBAND + ty;
            int p = atomicAdd(&s_pos[bin], 1);
            s_rec[s_off[bin] + p] = rec;
        }
    }
    __syncthreads();

    int* g = bins + b * BSTRIDE;
    for (int i = t; i < BIN_N; i += 512) { g[i] = s_cnt[i]; g[BIN_N + i] = s_off[i]; }
    const int total = s_off[BIN_N - 1] + s_cnt[BIN_N - 1];
    int4* gr = (int4*)(g + 2 * BIN_N);               // 16B-aligned
    for (int i = t; i < total; i += 512) gr[i] = s_rec[i];
}

// ---------------------------------------------------------------------------
// Phase B: one 512-thread block per (batch, class, band) slab. The bin's
// records are staged into LDS with ONE cooperative parallel load (removes
// the n-deep serial global-latency chain from the block's critical path),
// then the max-gather loop reads same-address LDS broadcasts. Store the
// contiguous 64 KB slab once; blockIdx order == memory order.
// ---------------------------------------------------------------------------
__global__ __launch_bounds__(512) void phaseB(
        float* __restrict__ out, const int* __restrict__ bins)
{
    const int bid = blockIdx.x;                 // 0 .. NBINS-1
    const int b   = bid / BIN_N;
    const int rem = bid - b * BIN_N;            // c*NBAND + band
    const int y0  = (rem & (NBAND - 1)) << 5;
    const int t   = threadIdx.x;

    __shared__ int4 s_rec[NOBJ];                // worst case: all 500 in one bin

    const int* g = bins + b * BSTRIDE;
    const int n   = __builtin_amdgcn_readfirstlane(g[rem]);
    const int off = __builtin_amdgcn_readfirstlane(g[BIN_N + rem]);
    const int4* rec = (const int4*)(g + 2 * BIN_N);

    // Cooperative stage: one parallel vector load instead of n serial ones.
    for (int i = t; i < n; i += 512) s_rec[i] = rec[off + i];

    const int col0  = (t & 127) << 2;                                  // 0..508
    const int r0    = __builtin_amdgcn_readfirstlane(t >> 7);          // 0..3
    const int wbase = __builtin_amdgcn_readfirstlane(((t >> 6) & 1) << 8); // 0 or 256

    float acc[8][4];
    #pragma unroll
    for (int s = 0; s < 8; ++s) {
        acc[s][0] = 0.f; acc[s][1] = 0.f; acc[s][2] = 0.f; acc[s][3] = 0.f;
    }

    __syncthreads();

    for (int it = 0; it < n; ++it) {
        int4 r = s_rec[it];                     // same-address LDS broadcast
        int cxi   = __builtin_amdgcn_readfirstlane(r.x);
        int cyi   = __builtin_amdgcn_readfirstlane(r.y);
        int rad   = __builtin_amdgcn_readfirstlane(r.z);
        float negInv = __int_as_float(__builtin_amdgcn_readfirstlane(r.w));

        // wave-uniform column-range early-out (wave covers [wbase, wbase+255])
        if (cxi + rad < wbase || cxi - rad > wbase + 255) continue;

        float cexp[4]; bool colin[4];
        #pragma unroll
        for (int k = 0; k < 4; ++k) {
            int rx = col0 + k - cxi;
            colin[k] = (rx >= -rad) && (rx <= rad);
            cexp[k]  = __expf((float)(rx * rx) * negInv);
        }

        #pragma unroll
        for (int s = 0; s < 8; ++s) {
            int ry = y0 + 4 * s + r0 - cyi;      // wave-uniform
            if (ry < -rad || ry > rad) continue; // scalar branch
            float rexp = __expf((float)(ry * ry) * negInv);
            #pragma unroll
            for (int k = 0; k < 4; ++k) {
                float gg = rexp * cexp[k];
                bool ok = colin[k] && (gg >= EPS_);
                acc[s][k] = ok ? fmaxf(acc[s][k], gg) : acc[s][k];
            }
        }
    }

    // contiguous 64 KB slab store; blockIdx order == memory order
    float4* out4 = (float4*)(out + (size_t)bid * (BAND_ * FW_));
    #pragma unroll
    for (int s = 0; s < 8; ++s)
        out4[s * 512 + t] = make_float4(acc[s][0], acc[s][1], acc[s][2], acc[s][3]);
}

// ---------------------------------------------------------------------------
// Fallback (known-correct fused kernel) if ws is too small.
// ---------------------------------------------------------------------------
__global__ __launch_bounds__(512) void fused(
        const float* __restrict__ gt, float* __restrict__ out)
{
    const int bid  = blockIdx.x;
    const int b    = bid / (NCLS * NBAND);
    const int rem  = bid - b * (NCLS * NBAND);
    const int myc  = rem >> 4;
    const int band = rem & (NBAND - 1);
    const int y0   = band << 5;

    __shared__ int  s_cnt;
    __shared__ int4 s_rec[NOBJ];

    if (threadIdx.x == 0) s_cnt = 0;
    __syncthreads();

    const int t = threadIdx.x;
    if (t < NOBJ) {
        const int obj = b * NOBJ + t;
        const float4 lo = *(const float4*)(gt + (size_t)obj * 8);
        const float4 hi = *(const float4*)(gt + (size_t)obj * 8 + 4);
        float coord_x, coord_y; int cxi, cyi, radius; bool valid;
        obj_params(lo.x, lo.y, lo.w, hi.x, coord_x, coord_y, cxi, cyi, radius, valid);
        int c = min(max((int)(hi.w - 1.0f), 0), NCLS - 1);

        if (myc == 0 && band == 0) {
            float vf = valid ? 1.f : 0.f;
            float4 rb0 = make_float4((coord_x - (float)cxi) * vf,
                                     (coord_y - (float)cyi) * vf,
                                     lo.z * vf,
                                     logf(fmaxf(lo.w, 1e-12f)) * vf);
            float4 rb1 = make_float4(logf(fmaxf(hi.x, 1e-12f)) * vf,
                                     logf(fmaxf(hi.y, 1e-12f)) * vf,
                                     cosf(hi.z) * vf,
                                     sinf(hi.z) * vf);
            float* rb = out + RETBOX_OFF + (size_t)obj * 8;
            *(float4*)(rb)     = rb0;
            *(float4*)(rb + 4) = rb1;
            out[INDS_OFF + obj] = valid ? (float)(cyi * FW_ + cxi) : 0.f;
            out[MASK_OFF + obj] = vf;
        }

        if (valid && c == myc &&
            (cyi + radius >= y0) && (cyi - radius <= y0 + BAND_ - 1)) {
            float sigma = (2.f * (float)radius + 1.f) / 6.f;
            float negInv = -1.0f / (2.f * sigma * sigma);
            int pos = atomicAdd(&s_cnt, 1);
            s_rec[pos] = make_int4(cxi, cyi, radius, __float_as_int(negInv));
        }
    }
    __syncthreads();

    const int col0  = (t & 127) << 2;
    const int r0    = __builtin_amdgcn_readfirstlane(t >> 7);
    const int wbase = __builtin_amdgcn_readfirstlane(((t >> 6) & 1) << 8);

    float acc[8][4];
    #pragma unroll
    for (int s = 0; s < 8; ++s) {
        acc[s][0] = 0.f; acc[s][1] = 0.f; acc[s][2] = 0.f; acc[s][3] = 0.f;
    }

    const int n = s_cnt;
    for (int it = 0; it < n; ++it) {
        int4 r = s_rec[it];
        int cxi   = __builtin_amdgcn_readfirstlane(r.x);
        int cyi   = __builtin_amdgcn_readfirstlane(r.y);
        int rad   = __builtin_amdgcn_readfirstlane(r.z);
        float negInv = __int_as_float(__builtin_amdgcn_readfirstlane(r.w));

        if (cxi + rad < wbase || cxi - rad > wbase + 255) continue;

        float cexp[4]; bool colin[4];
        #pragma unroll
        for (int k = 0; k < 4; ++k) {
            int rx = col0 + k - cxi;
            colin[k] = (rx >= -rad) && (rx <= rad);
            cexp[k]  = __expf((float)(rx * rx) * negInv);
        }

        #pragma unroll
        for (int s = 0; s < 8; ++s) {
            int ry = y0 + 4 * s + r0 - cyi;
            if (ry < -rad || ry > rad) continue;
            float rexp = __expf((float)(ry * ry) * negInv);
            #pragma unroll
            for (int k = 0; k < 4; ++k) {
                float gg = rexp * cexp[k];
                bool ok = colin[k] && (gg >= EPS_);
                acc[s][k] = ok ? fmaxf(acc[s][k], gg) : acc[s][k];
            }
        }
    }

    float4* out4 = (float4*)(out + (size_t)bid * (BAND_ * FW_));
    #pragma unroll
    for (int s = 0; s < 8; ++s)
        out4[s * 512 + t] = make_float4(acc[s][0], acc[s][1], acc[s][2], acc[s][3]);
}

extern "C" void kernel_launch(void* const* d_in, const int* in_sizes, int n_in,
                              void* d_out, int out_size, void* d_ws, size_t ws_size,
                              hipStream_t stream) {
    const float* gt = (const float*)d_in[0];
    float* out = (float*)d_out;

    if (ws_size >= WS_NEEDED) {
        int* bins = (int*)d_ws;
        phaseA<<<BATCH_, 512, 0, stream>>>(gt, out, bins);
        phaseB<<<NBINS, 512, 0, stream>>>(out, bins);
    } else {
        fused<<<NBINS, 512, 0, stream>>>(gt, out);
    }
}